// Round 1
// baseline (473.477 us; speedup 1.0000x reference)
//
#include <hip/hip_runtime.h>
#include <stdint.h>

typedef short bf16x8 __attribute__((ext_vector_type(8)));
typedef float f32x4 __attribute__((ext_vector_type(4)));

__device__ __forceinline__ unsigned short f2bf(float f) {
  union { float f; unsigned u; } x; x.f = f;
  unsigned r = x.u + 0x7FFFu + ((x.u >> 16) & 1u);
  return (unsigned short)(r >> 16);
}

typedef const __attribute__((address_space(1))) unsigned int* gptr_t;
typedef __attribute__((address_space(3))) unsigned int* lptr_t;
__device__ __forceinline__ void gll16(const void* g, void* l) {
  __builtin_amdgcn_global_load_lds((gptr_t)g, (lptr_t)l, 16, 0, 0);
}

// ---------------- W transpose: [K=1024][N=1024] fp32 -> [N][K] bf16 ----------
__global__ __launch_bounds__(1024) void wt_kernel(const float* __restrict__ Wq,
                                                  const float* __restrict__ Wk,
                                                  const float* __restrict__ Wv,
                                                  unsigned short* __restrict__ wt) {
  const float* W = blockIdx.z == 0 ? Wq : (blockIdx.z == 1 ? Wk : Wv);
  unsigned short* o = wt + (size_t)blockIdx.z * 1048576;
  __shared__ float t[32][33];
  int tx = threadIdx.x, ty = threadIdx.y;
  t[ty][tx] = W[(size_t)(blockIdx.y * 32 + ty) * 1024 + blockIdx.x * 32 + tx];
  __syncthreads();
  o[(size_t)(blockIdx.x * 32 + ty) * 1024 + blockIdx.y * 32 + tx] = f2bf(t[tx][ty]);
}

// ---------------- projection GEMM: C[8192,1024] = X @ W + b ------------------
// 128x128 tile, 4 waves (2x2 of 64x64), BK=64, 16x16x32 bf16 MFMA.
// LDS in fragment-linear layout: subtile (kt*8+t) * 1KB + lane*16B.
__global__ __launch_bounds__(256) void proj_kernel(
    const float* __restrict__ Xq, const float* __restrict__ Xk, const float* __restrict__ Xv,
    const unsigned short* __restrict__ wt,
    const float* __restrict__ bq, const float* __restrict__ bk, const float* __restrict__ bv,
    unsigned short* __restrict__ qo, unsigned short* __restrict__ ko, unsigned short* __restrict__ vo) {
  int p = blockIdx.z;
  const float* X = p == 0 ? Xq : (p == 1 ? Xk : Xv);
  const unsigned short* Wt = wt + (size_t)p * 1048576;
  const float* bias = p == 0 ? bq : (p == 1 ? bk : bv);
  unsigned short* out = p == 0 ? qo : (p == 1 ? ko : vo);

  __shared__ __align__(16) unsigned short abuf[8192];  // 16KB
  __shared__ __align__(16) unsigned short bbuf[8192];  // 16KB

  int tid = threadIdx.x;
  int lane = tid & 63, w = tid >> 6;
  int l15 = lane & 15, quad = lane >> 4;
  int wm = w >> 1, wn = w & 1;
  int m0 = blockIdx.x * 128, n0 = blockIdx.y * 128;

  f32x4 acc[4][4] = {};

  for (int kk = 0; kk < 16; ++kk) {
    int k0 = kk * 64;
    // stage B tile (Wt rows = n, contiguous k) via global_load_lds, frag layout
    for (int j = 0; j < 4; ++j) {
      int st = w * 4 + j;
      int kt = st >> 3, nt = st & 7;
      const unsigned short* g = Wt + (size_t)(n0 + nt * 16 + l15) * 1024 + k0 + kt * 32 + quad * 8;
      gll16(g, &bbuf[st * 512]);
    }
    // stage A tile with fp32->bf16 conversion, frag layout
    for (int i = 0; i < 4; ++i) {
      int s = tid * 4 + i;
      int st = s >> 6, l = s & 63;
      int kt = st >> 3, mt = st & 7;
      int m = mt * 16 + (l & 15);
      int kc = kt * 32 + ((l >> 4) << 3);
      const float* src = X + (size_t)(m0 + m) * 1024 + k0 + kc;
      float4 f0 = *(const float4*)src;
      float4 f1 = *(const float4*)(src + 4);
      bf16x8 v;
      v[0] = (short)f2bf(f0.x); v[1] = (short)f2bf(f0.y);
      v[2] = (short)f2bf(f0.z); v[3] = (short)f2bf(f0.w);
      v[4] = (short)f2bf(f1.x); v[5] = (short)f2bf(f1.y);
      v[6] = (short)f2bf(f1.z); v[7] = (short)f2bf(f1.w);
      *(bf16x8*)&abuf[s * 8] = v;
    }
    __syncthreads();
    for (int kt = 0; kt < 2; ++kt) {
      bf16x8 af[4], bfr[4];
      for (int i = 0; i < 4; ++i) af[i]  = *(const bf16x8*)&abuf[(kt * 8 + wm * 4 + i) * 512 + lane * 8];
      for (int j = 0; j < 4; ++j) bfr[j] = *(const bf16x8*)&bbuf[(kt * 8 + wn * 4 + j) * 512 + lane * 8];
      for (int i = 0; i < 4; ++i)
        for (int j = 0; j < 4; ++j)
          acc[i][j] = __builtin_amdgcn_mfma_f32_16x16x32_bf16(af[i], bfr[j], acc[i][j], 0, 0, 0);
    }
    __syncthreads();
  }

  // epilogue: +bias, cast bf16, scatter to q/k [B,H,S,64] or v^T [B,H,64,S]
  bool isv = (p == 2);
  for (int j = 0; j < 4; ++j) {
    int n = n0 + wn * 64 + j * 16 + l15;
    float bl = bias[n];
    int h = n >> 6, d = n & 63;
    for (int i = 0; i < 4; ++i) {
      for (int r = 0; r < 4; ++r) {
        int m = m0 + wm * 64 + i * 16 + quad * 4 + r;
        int b = m >> 11, s = m & 2047;
        float val = acc[i][j][r] + bl;
        size_t idx;
        if (isv) idx = ((size_t)((b * 16 + h) * 64 + d) << 11) + s;
        else     idx = ((size_t)((b * 16 + h) * 2048 + s) << 6) + d;
        out[idx] = f2bf(val);
      }
    }
  }
}

// ---------------- fused attention ------------------------------------------
// grid (S/128=16, H=16, B=4), 256 threads = 4 waves, each wave owns 32 q-rows.
// Per 128-key iteration: QK^T (MFMA) -> exp*mask -> P via LDS -> PV + ones-den.
__global__ __launch_bounds__(256) void attn_kernel(
    const unsigned short* __restrict__ q, const unsigned short* __restrict__ k,
    const unsigned short* __restrict__ vT, const float* __restrict__ mask,
    float* __restrict__ out) {
  int qb = blockIdx.x, h = blockIdx.y, b = blockIdx.z;
  int tid = threadIdx.x, lane = tid & 63, w = tid >> 6;
  int l15 = lane & 15, quad = lane >> 4;

  __shared__ __align__(16) unsigned short kls[8192];       // 16KB frag layout
  __shared__ __align__(16) unsigned short vls[8192];       // 16KB frag layout
  __shared__ __align__(16) unsigned short pls[4 * 32 * 136]; // 34KB, pad=8

  const unsigned short* qp = q + (size_t)(b * 16 + h) * 2048 * 64;
  const unsigned short* kp = k + (size_t)(b * 16 + h) * 2048 * 64;
  const unsigned short* vp = vT + (size_t)(b * 16 + h) * 64 * 2048;
  const float* mp = mask + (size_t)b * 2048;

  // Q fragments, held in registers for the whole kernel
  bf16x8 aq[2][2];
  for (int mt = 0; mt < 2; ++mt)
    for (int kt = 0; kt < 2; ++kt)
      aq[mt][kt] = *(const bf16x8*)(qp + (size_t)(qb * 128 + w * 32 + mt * 16 + l15) * 64 + kt * 32 + quad * 8);

  f32x4 oacc[2][4] = {};
  f32x4 dacc[2] = {};
  bf16x8 ones = {0x3F80, 0x3F80, 0x3F80, 0x3F80, 0x3F80, 0x3F80, 0x3F80, 0x3F80};

  unsigned short* myP = &pls[w * 32 * 136];

  for (int kb = 0; kb < 16; ++kb) {
    int kbase = kb * 128;
    // stage K tile [128 keys][64 dk] and V^T tile [64 dv][128 keys], frag layout
    for (int j = 0; j < 4; ++j) {
      int st = w * 4 + j;
      {
        int kt = st >> 3, nt = st & 7;
        const unsigned short* g = kp + (size_t)(kbase + nt * 16 + l15) * 64 + kt * 32 + quad * 8;
        gll16(g, &kls[st * 512]);
      }
      {
        int kt2 = st >> 2, nt2 = st & 3;
        const unsigned short* g = vp + (size_t)(nt2 * 16 + l15) * 2048 + kbase + kt2 * 32 + quad * 8;
        gll16(g, &vls[st * 512]);
      }
    }
    __syncthreads();

    // S = Q K^T  (2 m-tiles x 8 n-tiles x 2 k-tiles)
    f32x4 sacc[2][8] = {};
    for (int nt = 0; nt < 8; ++nt)
      for (int kt = 0; kt < 2; ++kt) {
        bf16x8 bk = *(const bf16x8*)&kls[(kt * 8 + nt) * 512 + lane * 8];
        sacc[0][nt] = __builtin_amdgcn_mfma_f32_16x16x32_bf16(aq[0][kt], bk, sacc[0][nt], 0, 0, 0);
        sacc[1][nt] = __builtin_amdgcn_mfma_f32_16x16x32_bf16(aq[1][kt], bk, sacc[1][nt], 0, 0, 0);
      }

    // P = exp(S/8) * mask[key]  (raw exp, faithful to reference), to LDS bf16
    for (int nt = 0; nt < 8; ++nt) {
      float mval = mp[kbase + nt * 16 + l15];
      int col = nt * 16 + l15;
      for (int mt = 0; mt < 2; ++mt) {
        int row0 = mt * 16 + quad * 4;
        for (int r = 0; r < 4; ++r) {
          float e = __expf(sacc[mt][nt][r] * 0.125f) * mval;
          myP[(row0 + r) * 136 + col] = f2bf(e);
        }
      }
    }

    // O += P V, den += P @ ones  (wave-local P; compiler inserts lgkm waits)
    for (int kt = 0; kt < 4; ++kt) {
      bf16x8 pa[2];
      for (int mt = 0; mt < 2; ++mt)
        pa[mt] = *(const bf16x8*)&myP[(mt * 16 + l15) * 136 + kt * 32 + quad * 8];
      dacc[0] = __builtin_amdgcn_mfma_f32_16x16x32_bf16(pa[0], ones, dacc[0], 0, 0, 0);
      dacc[1] = __builtin_amdgcn_mfma_f32_16x16x32_bf16(pa[1], ones, dacc[1], 0, 0, 0);
      for (int nt = 0; nt < 4; ++nt) {
        bf16x8 bv = *(const bf16x8*)&vls[(kt * 4 + nt) * 512 + lane * 8];
        oacc[0][nt] = __builtin_amdgcn_mfma_f32_16x16x32_bf16(pa[0], bv, oacc[0][nt], 0, 0, 0);
        oacc[1][nt] = __builtin_amdgcn_mfma_f32_16x16x32_bf16(pa[1], bv, oacc[1][nt], 0, 0, 0);
      }
    }
    __syncthreads();
  }

  // epilogue: out[b][s][h*64+dv] = O / (den + 1e-8), fp32
  for (int mt = 0; mt < 2; ++mt)
    for (int r = 0; r < 4; ++r) {
      int s = qb * 128 + w * 32 + mt * 16 + quad * 4 + r;
      float rden = 1.0f / (dacc[mt][r] + 1e-8f);
      for (int nt = 0; nt < 4; ++nt) {
        int dv = nt * 16 + l15;
        out[(size_t)(b * 2048 + s) * 1024 + h * 64 + dv] = oacc[mt][nt][r] * rden;
      }
    }
}

extern "C" void kernel_launch(void* const* d_in, const int* in_sizes, int n_in,
                              void* d_out, int out_size, void* d_ws, size_t ws_size,
                              hipStream_t stream) {
  const float* Q    = (const float*)d_in[0];
  const float* K    = (const float*)d_in[1];
  const float* V    = (const float*)d_in[2];
  const float* mask = (const float*)d_in[3];
  const float* Wq   = (const float*)d_in[4];
  const float* bq   = (const float*)d_in[5];
  const float* Wk   = (const float*)d_in[6];
  const float* bk   = (const float*)d_in[7];
  const float* Wv   = (const float*)d_in[8];
  const float* bv   = (const float*)d_in[9];

  char* ws = (char*)d_ws;
  unsigned short* wt = (unsigned short*)ws;                  // 3 x 2MB bf16 W^T
  unsigned short* qb = (unsigned short*)(ws + 6291456);      // 16MB [B,H,S,64]
  unsigned short* kb = (unsigned short*)(ws + 23068672);     // 16MB [B,H,S,64]
  unsigned short* vb = (unsigned short*)(ws + 39845888);     // 16MB [B,H,64,S]

  hipLaunchKernelGGL(wt_kernel, dim3(32, 32, 3), dim3(32, 32), 0, stream, Wq, Wk, Wv, wt);
  hipLaunchKernelGGL(proj_kernel, dim3(64, 8, 3), dim3(256), 0, stream,
                     Q, K, V, wt, bq, bk, bv, qb, kb, vb);
  hipLaunchKernelGGL(attn_kernel, dim3(16, 16, 4), dim3(256), 0, stream,
                     qb, kb, vb, mask, (float*)d_out);
}

// Round 2
// 436.372 us; speedup vs baseline: 1.0850x; 1.0850x over previous
//
#include <hip/hip_runtime.h>
#include <hip/hip_bf16.h>
#include <stdint.h>

typedef short bf16x8 __attribute__((ext_vector_type(8)));
typedef float f32x4 __attribute__((ext_vector_type(4)));
typedef unsigned int u32x2 __attribute__((ext_vector_type(2)));
typedef unsigned int u32x4 __attribute__((ext_vector_type(4)));

__device__ __forceinline__ unsigned short f2bf(float f) {
  union { float f; unsigned u; } x; x.f = f;
  unsigned r = x.u + 0x7FFFu + ((x.u >> 16) & 1u);
  return (unsigned short)(r >> 16);
}

// packed 2xf32 -> 2xbf16 (v_cvt_pk_bf16_f32 on gfx950)
__device__ __forceinline__ unsigned pk2bf(float a, float b) {
  union { __hip_bfloat162 h; unsigned u; } x;
  x.h = __float22bfloat162_rn(make_float2(a, b));
  return x.u;
}

typedef const __attribute__((address_space(1))) unsigned int* gptr_t;
typedef __attribute__((address_space(3))) unsigned int* lptr_t;
__device__ __forceinline__ void gll16(const void* g, void* l) {
  __builtin_amdgcn_global_load_lds((gptr_t)g, (lptr_t)l, 16, 0, 0);
}

// ---------------- W transpose: [K=1024][N=1024] fp32 -> [N][K] bf16 ----------
__global__ __launch_bounds__(1024) void wt_kernel(const float* __restrict__ Wq,
                                                  const float* __restrict__ Wk,
                                                  const float* __restrict__ Wv,
                                                  unsigned short* __restrict__ wt) {
  const float* W = blockIdx.z == 0 ? Wq : (blockIdx.z == 1 ? Wk : Wv);
  unsigned short* o = wt + (size_t)blockIdx.z * 1048576;
  __shared__ float t[32][33];
  int tx = threadIdx.x, ty = threadIdx.y;
  t[ty][tx] = W[(size_t)(blockIdx.y * 32 + ty) * 1024 + blockIdx.x * 32 + tx];
  __syncthreads();
  o[(size_t)(blockIdx.x * 32 + ty) * 1024 + blockIdx.y * 32 + tx] = f2bf(t[tx][ty]);
}

// ---------------- X fp32 -> bf16 (Q,K,V concatenated) ------------------------
__global__ __launch_bounds__(256) void cvt_kernel(const float* __restrict__ Q,
                                                  const float* __restrict__ K,
                                                  const float* __restrict__ V,
                                                  unsigned short* __restrict__ out) {
  int y = blockIdx.y;
  const float* s = y == 0 ? Q : (y == 1 ? K : V);
  unsigned short* o = out + (size_t)y * 8388608;
  size_t idx = ((size_t)blockIdx.x * 256 + threadIdx.x) * 8;
  float4 f0 = *(const float4*)(s + idx);
  float4 f1 = *(const float4*)(s + idx + 4);
  u32x4 r = {pk2bf(f0.x, f0.y), pk2bf(f0.z, f0.w), pk2bf(f1.x, f1.y), pk2bf(f1.z, f1.w)};
  *(u32x4*)(o + idx) = r;
}

// ---------------- projection GEMM: C[8192,1024] = Xb @ W^T + b ---------------
// pure-bf16 m97 pattern: global_load_lds(16) both operands, 128x128 tile, BK=64.
__global__ __launch_bounds__(256) void proj_kernel(
    const unsigned short* __restrict__ Xb, const unsigned short* __restrict__ wt,
    const float* __restrict__ bq, const float* __restrict__ bk, const float* __restrict__ bv,
    unsigned short* __restrict__ qo, unsigned short* __restrict__ ko, unsigned short* __restrict__ vo) {
  int p = blockIdx.z;
  const unsigned short* X = Xb + (size_t)p * 8388608;
  const unsigned short* Wt = wt + (size_t)p * 1048576;
  const float* bias = p == 0 ? bq : (p == 1 ? bk : bv);
  unsigned short* out = p == 0 ? qo : (p == 1 ? ko : vo);

  __shared__ __align__(16) unsigned short abuf[8192];  // 16KB
  __shared__ __align__(16) unsigned short bbuf[8192];  // 16KB

  int tid = threadIdx.x;
  int lane = tid & 63, w = tid >> 6;
  int l15 = lane & 15, quad = lane >> 4;
  int wm = w >> 1, wn = w & 1;
  int m0 = blockIdx.x * 128, n0 = blockIdx.y * 128;

  f32x4 acc[4][4] = {};

  for (int kk = 0; kk < 16; ++kk) {
    int k0 = kk * 64;
    for (int j = 0; j < 4; ++j) {
      int stj = w * 4 + j;
      int kt = stj >> 3, t = stj & 7;
      gll16(Wt + (size_t)(n0 + t * 16 + l15) * 1024 + k0 + kt * 32 + quad * 8, &bbuf[stj * 512]);
      gll16(X + (size_t)(m0 + t * 16 + l15) * 1024 + k0 + kt * 32 + quad * 8, &abuf[stj * 512]);
    }
    __syncthreads();
    for (int kt = 0; kt < 2; ++kt) {
      bf16x8 af[4], bfr[4];
      for (int i = 0; i < 4; ++i) af[i]  = *(const bf16x8*)&abuf[(kt * 8 + wm * 4 + i) * 512 + lane * 8];
      for (int j = 0; j < 4; ++j) bfr[j] = *(const bf16x8*)&bbuf[(kt * 8 + wn * 4 + j) * 512 + lane * 8];
      for (int i = 0; i < 4; ++i)
        for (int j = 0; j < 4; ++j)
          acc[i][j] = __builtin_amdgcn_mfma_f32_16x16x32_bf16(af[i], bfr[j], acc[i][j], 0, 0, 0);
    }
    __syncthreads();
  }

  // epilogue: +bias, cast bf16, scatter to q/k [B,H,S,64] or v^T [B,H,64,S]
  bool isv = (p == 2);
  for (int j = 0; j < 4; ++j) {
    int n = n0 + wn * 64 + j * 16 + l15;
    float bl = bias[n];
    int h = n >> 6, d = n & 63;
    for (int i = 0; i < 4; ++i) {
      for (int r = 0; r < 4; ++r) {
        int m = m0 + wm * 64 + i * 16 + quad * 4 + r;
        int b = m >> 11, s = m & 2047;
        float val = acc[i][j][r] + bl;
        size_t idx;
        if (isv) idx = ((size_t)((b * 16 + h) * 64 + d) << 11) + s;
        else     idx = ((size_t)((b * 16 + h) * 2048 + s) << 6) + d;
        out[idx] = f2bf(val);
      }
    }
  }
}

// ---------------- fused attention ------------------------------------------
// grid (16,16,4), 256 thr = 4 waves, wave owns 32 q-rows.
// Computes S^T = K Q^T so P exits MFMA with col=qrow — matches PV A-operand m.
// P packed to bf16 pairs, staged per-wave in LDS aliased over the K tile.
__global__ __launch_bounds__(256, 3) void attn_kernel(
    const unsigned short* __restrict__ q, const unsigned short* __restrict__ k,
    const unsigned short* __restrict__ vT, const float* __restrict__ mask,
    float* __restrict__ out) {
  int qb = blockIdx.x, h = blockIdx.y, b = blockIdx.z;
  int tid = threadIdx.x, lane = tid & 63, w = tid >> 6;
  int l15 = lane & 15, quad = lane >> 4;

  __shared__ __align__(16) unsigned short un[16384];  // 32KB: K tile (16KB) ∪ P (32KB)
  __shared__ __align__(16) unsigned short vls[8192];  // 16KB

  const unsigned short* qp = q + (size_t)(b * 16 + h) * 2048 * 64;
  const unsigned short* kp = k + (size_t)(b * 16 + h) * 2048 * 64;
  const unsigned short* vp = vT + (size_t)(b * 16 + h) * 64 * 2048;
  const float* mp = mask + (size_t)b * 2048;

  // Q fragments (as B-operand of S^T): lane holds qrow=l15, d=quad*8+j
  bf16x8 aq[2][2];
  for (int nt = 0; nt < 2; ++nt)
    for (int kt = 0; kt < 2; ++kt)
      aq[nt][kt] = *(const bf16x8*)(qp + (size_t)(qb * 128 + w * 32 + nt * 16 + l15) * 64 + kt * 32 + quad * 8);

  f32x4 oacc[2][4] = {};
  f32x4 dacc[2] = {};
  bf16x8 ones = {0x3F80, 0x3F80, 0x3F80, 0x3F80, 0x3F80, 0x3F80, 0x3F80, 0x3F80};

  unsigned short* pw = &un[w * 4096];  // 8KB per-wave P region

  for (int kb = 0; kb < 16; ++kb) {
    int kbase = kb * 128;
    // stage K [128 keys][64] and V^T [64 dv][128 keys], frag layout
    for (int j = 0; j < 4; ++j) {
      int stj = w * 4 + j;
      int kt = stj >> 3, t = stj & 7;
      gll16(kp + (size_t)(kbase + t * 16 + l15) * 64 + kt * 32 + quad * 8, &un[stj * 512]);
      int kt2 = stj >> 2, t2 = stj & 3;
      gll16(vp + (size_t)(t2 * 16 + l15) * 2048 + kbase + kt2 * 32 + quad * 8, &vls[stj * 512]);
    }
    __syncthreads();

    // S^T = K Q^T : D col = qrow (l15), row = key (quad*4+r)
    f32x4 sacc[8][2] = {};
    for (int mt16 = 0; mt16 < 8; ++mt16)
      for (int kt = 0; kt < 2; ++kt) {
        bf16x8 ak = *(const bf16x8*)&un[(kt * 8 + mt16) * 512 + lane * 8];
        sacc[mt16][0] = __builtin_amdgcn_mfma_f32_16x16x32_bf16(ak, aq[0][kt], sacc[mt16][0], 0, 0, 0);
        sacc[mt16][1] = __builtin_amdgcn_mfma_f32_16x16x32_bf16(ak, aq[1][kt], sacc[mt16][1], 0, 0, 0);
      }

    __syncthreads();  // all waves done reading K tile; P may overwrite it

    // P^T values: exp(S/8)*mask[key], packed bf16 pairs (r01,r23) -> LDS b64
    for (int mt16 = 0; mt16 < 8; ++mt16) {
      float4 mv = *(const float4*)&mp[kbase + mt16 * 16 + quad * 4];
      const float* mm = (const float*)&mv;
      for (int nt = 0; nt < 2; ++nt) {
        float e0 = __expf(sacc[mt16][nt][0] * 0.125f) * mm[0];
        float e1 = __expf(sacc[mt16][nt][1] * 0.125f) * mm[1];
        float e2 = __expf(sacc[mt16][nt][2] * 0.125f) * mm[2];
        float e3 = __expf(sacc[mt16][nt][3] * 0.125f) * mm[3];
        u32x2 wv = {pk2bf(e0, e1), pk2bf(e2, e3)};
        *(u32x2*)&pw[(nt * 8 + mt16) * 256 + lane * 4] = wv;
      }
    }

    // O += P V, den += P @ ones. A-frag: m=l15 (qrow), keys kt*32+quad*8+j
    for (int kt = 0; kt < 4; ++kt) {
      int t = kt * 2 + (quad >> 1);
      int srcl = ((quad & 1) * 2) * 16 + l15;
      bf16x8 pa[2];
      for (int mt = 0; mt < 2; ++mt) {
        union { u32x2 p[2]; bf16x8 v; } u;
        int base = (mt * 8 + t) * 256 + srcl * 4;
        u.p[0] = *(const u32x2*)&pw[base];
        u.p[1] = *(const u32x2*)&pw[base + 64];
        pa[mt] = u.v;
      }
      dacc[0] = __builtin_amdgcn_mfma_f32_16x16x32_bf16(pa[0], ones, dacc[0], 0, 0, 0);
      dacc[1] = __builtin_amdgcn_mfma_f32_16x16x32_bf16(pa[1], ones, dacc[1], 0, 0, 0);
      for (int nt = 0; nt < 4; ++nt) {
        bf16x8 bv = *(const bf16x8*)&vls[(kt * 4 + nt) * 512 + lane * 8];
        oacc[0][nt] = __builtin_amdgcn_mfma_f32_16x16x32_bf16(pa[0], bv, oacc[0][nt], 0, 0, 0);
        oacc[1][nt] = __builtin_amdgcn_mfma_f32_16x16x32_bf16(pa[1], bv, oacc[1][nt], 0, 0, 0);
      }
    }
    __syncthreads();
  }

  // epilogue: out[b][s][h*64+dv] = O / (den + 1e-8), fp32
  for (int mt = 0; mt < 2; ++mt)
    for (int r = 0; r < 4; ++r) {
      int s = qb * 128 + w * 32 + mt * 16 + quad * 4 + r;
      float rden = 1.0f / (dacc[mt][r] + 1e-8f);
      for (int nt = 0; nt < 4; ++nt) {
        int dv = nt * 16 + l15;
        out[(size_t)(b * 2048 + s) * 1024 + h * 64 + dv] = oacc[mt][nt][r] * rden;
      }
    }
}

extern "C" void kernel_launch(void* const* d_in, const int* in_sizes, int n_in,
                              void* d_out, int out_size, void* d_ws, size_t ws_size,
                              hipStream_t stream) {
  const float* Q    = (const float*)d_in[0];
  const float* K    = (const float*)d_in[1];
  const float* V    = (const float*)d_in[2];
  const float* mask = (const float*)d_in[3];
  const float* Wq   = (const float*)d_in[4];
  const float* bq   = (const float*)d_in[5];
  const float* Wk   = (const float*)d_in[6];
  const float* bk   = (const float*)d_in[7];
  const float* Wv   = (const float*)d_in[8];
  const float* bv   = (const float*)d_in[9];

  char* ws = (char*)d_ws;
  unsigned short* wt = (unsigned short*)ws;                  // 6MB: 3 x bf16 W^T
  unsigned short* qb = (unsigned short*)(ws + 6291456);      // 16MB [B,H,S,64]
  unsigned short* kb = (unsigned short*)(ws + 23068672);     // 16MB [B,H,S,64]
  unsigned short* vb = (unsigned short*)(ws + 39845888);     // 16MB [B,H,64,S]
  unsigned short* xb = (unsigned short*)(ws + 56623104);     // 48MB bf16 Q,K,V

  hipLaunchKernelGGL(wt_kernel, dim3(32, 32, 3), dim3(32, 32), 0, stream, Wq, Wk, Wv, wt);
  hipLaunchKernelGGL(cvt_kernel, dim3(4096, 3), dim3(256), 0, stream, Q, K, V, xb);
  hipLaunchKernelGGL(proj_kernel, dim3(64, 8, 3), dim3(256), 0, stream,
                     xb, wt, bq, bk, bv, qb, kb, vb);
  hipLaunchKernelGGL(attn_kernel, dim3(16, 16, 4), dim3(256), 0, stream,
                     qb, kb, vb, mask, (float*)d_out);
}